// Round 5
// baseline (2485.425 us; speedup 1.0000x reference)
//
#include <hip/hip_runtime.h>
#include <hip/hip_bf16.h>
#include <stdint.h>

// ---------------------------------------------------------------------------
// EncoderBiLSTM on MI355X.  RESET=32 => 16 independent chunks of 32 steps.
// Rows r = chunk*64 + b (1024/dir), t = chunk*32 + s.
// R5 restructure: hoist the non-recurrent x-projection out of the sequential
// chain.  xp[s][r][n4] = x_s @ Wx^T + bias (fp16, gate-permuted cols), done in
// 16 batched GEMMs (M=4096,N=4096,K=1024).  Step kernels only do the h-GEMM
// (K=512) + xp add + cell update.  L1 lags L0 by 4 steps; xp1 batches (A =
// out0 ring) run every 4th launch.  Rings: xp 12 slices, out0 8 slices.
// Gate permutation: n = (j>>4)*64 + g*16 + (j&15), g in {i,f,g,o}.
// ---------------------------------------------------------------------------

typedef _Float16 half8 __attribute__((ext_vector_type(8)));
typedef _Float16 half4v __attribute__((ext_vector_type(4)));
typedef float float4v __attribute__((ext_vector_type(4)));

#define AS1C(p) ((const __attribute__((address_space(1))) void*)(p))
#define AS3(p)  ((__attribute__((address_space(3))) void*)(p))

__device__ __forceinline__ float sigm(float x){ return 1.0f/(1.0f + __expf(-x)); }
__device__ __forceinline__ float tanh_f(float x){ return 2.0f/(1.0f + __expf(-2.0f*x)) - 1.0f; }

// ---- embedding: emb[t][b][d] = (Ert[rt]+Ere[re]+Erm[rm]) as fp16 -----------
__global__ __launch_bounds__(256) void k_embed(
    const int* __restrict__ rt, const int* __restrict__ re, const int* __restrict__ rm,
    const float* __restrict__ Ert, const float* __restrict__ Ere, const float* __restrict__ Erm,
    _Float16* __restrict__ emb)
{
  size_t idx = (size_t)blockIdx.x * 256 + threadIdx.x;   // 16384 blocks
  int dq = (int)(idx & 255);
  size_t bt = idx >> 8;                                  // b*512 + t, b<32
  size_t bt2 = bt + 16384;                               // b+32
  int a0 = rt[bt],  a1 = re[bt],  a2 = rm[bt];
  int b0 = rt[bt2], b1 = re[bt2], b2 = rm[bt2];
  float4 u0 = ((const float4*)Ert)[(size_t)a0 * 256 + dq];
  float4 u1 = ((const float4*)Ere)[(size_t)a1 * 256 + dq];
  float4 u2 = ((const float4*)Erm)[(size_t)a2 * 256 + dq];
  float4 w0 = ((const float4*)Ert)[(size_t)b0 * 256 + dq];
  float4 w1 = ((const float4*)Ere)[(size_t)b1 * 256 + dq];
  float4 w2 = ((const float4*)Erm)[(size_t)b2 * 256 + dq];
  half4v h, g;
  h[0] = (_Float16)(u0.x + u1.x + u2.x);
  h[1] = (_Float16)(u0.y + u1.y + u2.y);
  h[2] = (_Float16)(u0.z + u1.z + u2.z);
  h[3] = (_Float16)(u0.w + u1.w + u2.w);
  g[0] = (_Float16)(w0.x + w1.x + w2.x);
  g[1] = (_Float16)(w0.y + w1.y + w2.y);
  g[2] = (_Float16)(w0.z + w1.z + w2.z);
  g[3] = (_Float16)(w0.w + w1.w + w2.w);
  int b_ = (int)(bt >> 9), t_ = (int)(bt & 511);
  ((half4v*)emb)[((size_t)t_ * 64 + b_) * 256 + dq] = h;
  ((half4v*)emb)[((size_t)t_ * 64 + (b_ + 32)) * 256 + dq] = g;
}

// ---- weight prep: permuted fp16 Wx[ld][n][1024], Wh[ld][n][512] ------------
__global__ __launch_bounds__(256) void k_prepw(
    const float* __restrict__ Wih, const float* __restrict__ Whh,
    _Float16* __restrict__ Wx, _Float16* __restrict__ Wh)
{
  int bid = blockIdx.x;            // 0..8191 = ld*2048 + n
  int ld = bid >> 11, n = bid & 2047;
  int g = (n >> 4) & 3;
  int j = ((n >> 6) << 4) | (n & 15);
  int srow = g * 512 + j;
  const float* sx = Wih + ((size_t)ld * 2048 + srow) * 1024;
  const float* sh = Whh + ((size_t)ld * 2048 + srow) * 512;
  _Float16* dx = Wx + (size_t)bid * 1024;
  _Float16* dh = Wh + (size_t)bid * 512;
  for (int k = threadIdx.x; k < 1024; k += 256) dx[k] = (_Float16)sx[k];
  for (int k = threadIdx.x; k < 512;  k += 256) dh[k] = (_Float16)sh[k];
}

__global__ __launch_bounds__(256) void k_prepb(
    const float* __restrict__ bih, const float* __restrict__ bhh,
    float* __restrict__ biasc)
{
  int idx = blockIdx.x * 256 + threadIdx.x;   // 8192
  int ld = idx >> 11, n = idx & 2047;
  int g = (n >> 4) & 3;
  int j = ((n >> 6) << 4) | (n & 15);
  int srow = ld * 2048 + g * 512 + j;
  biasc[idx] = bih[srow] + bhh[srow];
}

// ---- state init per layer: chunk0 rows from h0/c0, rest zero ---------------
__global__ __launch_bounds__(256) void k_init(
    int layer, const float* __restrict__ h0, const float* __restrict__ c0,
    _Float16* __restrict__ hbuf, float* __restrict__ cbuf)
{
  int idx = blockIdx.x * 256 + threadIdx.x;   // 2*1024*512
  int dir = idx >> 19;
  int rj = idx & ((1 << 19) - 1);
  int r = rj >> 9, j = rj & 511;
  float hv = 0.f, cv = 0.f;
  if (r < 64) {
    size_t s0 = ((size_t)(layer * 2 + dir) * 64 + r) * 512 + j;
    hv = h0[s0]; cv = c0[s0];
  }
  hbuf[idx] = (_Float16)hv;
  cbuf[idx] = cv;
}

// ---- xproj batch GEMM: M=4096 (4 slices), N=4096, K=1024 -------------------
// grid (32 n-tiles, 32 m-tiles), 512 thr = 8 waves (wm=w>>1, wn=w&1).
// layer selects A source: 0 -> emb (t-addressed), 1 -> out0ring (slot s&7).
// Output xpring[s%12][r][n4] = acc + bias, fp16.
__global__ __launch_bounds__(512, 4) void k_xp(
    int layer, int batch,
    const _Float16* __restrict__ emb, const _Float16* __restrict__ out0ring,
    const _Float16* __restrict__ Wx, const float* __restrict__ biasc,
    _Float16* __restrict__ xpring)
{
  __shared__ __align__(16) _Float16 smem[32768];  // 2 x (A 16K | B 16K) bytes
  const int tid = threadIdx.x;
  const int w = tid >> 6, l = tid & 63;
  const int n0 = blockIdx.x * 128;
  const int by = blockIdx.y;
  const int sIdx = by >> 3;
  const int rbase = (by & 7) * 128;
  const int s = batch * 4 + sIdx;
  const int slot = s % 12;

  const char* pG[4]; uint32_t ldsoff[4];
  #pragma unroll
  for (int ii = 0; ii < 4; ++ii) {
    int instr = w * 4 + ii;                  // waves 0-3: A, waves 4-7: B
    if (instr < 16) {
      int c = instr * 64 + l;
      int row = c & 127, kc = c >> 7;        // kc in [0,8)
      int r = rbase + row;
      if (layer == 0) {
        int t = (r >> 6) * 32 + s;
        pG[ii] = (const char*)(emb + ((size_t)t * 64 + (r & 63)) * 1024 + kc * 8);
      } else {
        pG[ii] = (const char*)(out0ring + ((size_t)(s & 7) * 1024 + r) * 1024 + kc * 8);
      }
      ldsoff[ii] = (uint32_t)instr * 1024u;
    } else {
      int c = (instr - 16) * 64 + l;
      int nl = c & 127, kc = c >> 7;
      int ng = n0 + nl;
      int ldb = layer * 2 + (ng >> 11);
      pG[ii] = (const char*)(Wx + ((size_t)ldb * 2048 + (ng & 2047)) * 1024 + kc * 8);
      ldsoff[ii] = 16384u + (uint32_t)(instr - 16) * 1024u;
    }
  }

  const int wm = w >> 1, wn = w & 1;
  float4v acc[2][4];
  const float4v vzero = {0.f, 0.f, 0.f, 0.f};
  #pragma unroll
  for (int mf = 0; mf < 2; ++mf)
    #pragma unroll
    for (int nf = 0; nf < 4; ++nf) acc[mf][nf] = vzero;

  auto stage = [&](int it, int buf) {
    #pragma unroll
    for (int ii = 0; ii < 4; ++ii)
      __builtin_amdgcn_global_load_lds(AS1C(pG[ii] + (size_t)it * 128),
          AS3(((char*)smem) + (size_t)buf * 32768 + ldsoff[ii]), 16, 0, 0);
  };

  stage(0, 0);
  #pragma unroll 2
  for (int it = 0; it < 16; ++it) {
    const int cur = it & 1;
    if (it < 15) {
      stage(it + 1, cur ^ 1);
      asm volatile("s_waitcnt vmcnt(4)" ::: "memory");
    } else {
      asm volatile("s_waitcnt vmcnt(0)" ::: "memory");
    }
    __builtin_amdgcn_sched_barrier(0);
    __builtin_amdgcn_s_barrier();
    __builtin_amdgcn_sched_barrier(0);
    const _Float16* sA = smem + (size_t)cur * 16384;
    const _Float16* sB = sA + 8192;
    __builtin_amdgcn_s_setprio(1);
    #pragma unroll
    for (int kk = 0; kk < 64; kk += 32) {
      const int kcb = (kk >> 3) + (l >> 4);
      half8 a[2], b[4];
      #pragma unroll
      for (int mf = 0; mf < 2; ++mf)
        a[mf] = *(const half8*)(sA + ((size_t)kcb * 128 + wm * 32 + mf * 16 + (l & 15)) * 8);
      #pragma unroll
      for (int nf = 0; nf < 4; ++nf)
        b[nf] = *(const half8*)(sB + ((size_t)kcb * 128 + wn * 64 + nf * 16 + (l & 15)) * 8);
      #pragma unroll
      for (int mf = 0; mf < 2; ++mf)
        #pragma unroll
        for (int nf = 0; nf < 4; ++nf)
          acc[mf][nf] = __builtin_amdgcn_mfma_f32_16x16x32_f16(a[mf], b[nf], acc[mf][nf], 0, 0, 0);
    }
    __builtin_amdgcn_s_setprio(0);
    asm volatile("s_waitcnt lgkmcnt(0)" ::: "memory");
    __builtin_amdgcn_sched_barrier(0);
    __builtin_amdgcn_s_barrier();
    __builtin_amdgcn_sched_barrier(0);
  }

  const int jj = l & 15;
  const int ldb = layer * 2 + (n0 >> 11);   // uniform per block
  float bias[4];
  #pragma unroll
  for (int nf = 0; nf < 4; ++nf)
    bias[nf] = biasc[ldb * 2048 + ((n0 & 2047) + wn * 64 + nf * 16 + jj)];
  #pragma unroll
  for (int mf = 0; mf < 2; ++mf)
    #pragma unroll
    for (int reg = 0; reg < 4; ++reg) {
      int row = rbase + wm * 32 + mf * 16 + (l >> 4) * 4 + reg;
      #pragma unroll
      for (int nf = 0; nf < 4; ++nf) {
        int n4 = n0 + wn * 64 + nf * 16 + jj;
        xpring[((size_t)slot * 1024 + row) * 4096 + n4] =
            (_Float16)(acc[mf][nf][reg] + bias[nf]);
      }
    }
}

// ---- recurrent step: h-GEMM (K=512) + xp add + LSTM cell -------------------
// grid (32, 8, 2): x = nb (dir*16 + ntile), y = m-tile, z = layer.
__global__ __launch_bounds__(512, 4) void k_step(
    int s0, int s1,
    _Float16* __restrict__ out0ring,     // [8 slots][1024 r][1024] (L0 dest / xp1 src)
    float* __restrict__ outs,            // [B][T][1024] (L1 dest, fp32)
    _Float16* __restrict__ hbAll,        // 4 bufs: (layer*2+parity)*2^20 halves
    float* __restrict__ cbAll,           // 2 bufs: layer*2^20 floats
    const _Float16* __restrict__ Wh,     // [4][2048][512]
    const _Float16* __restrict__ xp0ring,// [12][1024][4096] fp16 (bias folded)
    const _Float16* __restrict__ xp1ring,
    float* __restrict__ hT, float* __restrict__ cT)
{
  const int layer = blockIdx.z;
  const int s = layer ? s1 : s0;
  if ((unsigned)s > 31u) return;         // uniform; before any barrier

  const _Float16* xp   = (layer ? xp1ring : xp0ring) + (size_t)(s % 12) * 1024 * 4096;
  const _Float16* hin  = hbAll + ((size_t)(layer * 2 + (s & 1))) * 1048576;
  _Float16*       hout = hbAll + ((size_t)(layer * 2 + ((s & 1) ^ 1))) * 1048576;
  float*          cbuf = cbAll + (size_t)layer * 1048576;

  __shared__ __align__(16) _Float16 smem[32768];
  const int tid = threadIdx.x;
  const int w = tid >> 6, l = tid & 63;
  const int nb = blockIdx.x;
  const int m0 = blockIdx.y * 128;
  const int dir = nb >> 4;
  const int n0 = (nb & 15) * 128;
  const int ld = layer * 2 + dir;

  const char* pG[4]; uint32_t ldsoff[4];
  #pragma unroll
  for (int ii = 0; ii < 4; ++ii) {
    int instr = w * 4 + ii;
    if (instr < 16) {                      // A tile: h rows
      int c = instr * 64 + l;
      int row = c & 127, kc = c >> 7;
      int r = m0 + row;
      pG[ii] = (const char*)(hin + ((size_t)dir * 1024 + r) * 512 + kc * 8);
      ldsoff[ii] = (uint32_t)instr * 1024u;
    } else {                               // B tile: Wh rows
      int c = (instr - 16) * 64 + l;
      int nl = c & 127, kc = c >> 7;
      pG[ii] = (const char*)(Wh + ((size_t)ld * 2048 + n0 + nl) * 512 + kc * 8);
      ldsoff[ii] = 16384u + (uint32_t)(instr - 16) * 1024u;
    }
  }

  const int wm = w >> 1, wn = w & 1;
  float4v acc[2][4];
  const float4v vzero = {0.f, 0.f, 0.f, 0.f};
  #pragma unroll
  for (int mf = 0; mf < 2; ++mf)
    #pragma unroll
    for (int nf = 0; nf < 4; ++nf) acc[mf][nf] = vzero;

  auto stage = [&](int it, int buf) {
    #pragma unroll
    for (int ii = 0; ii < 4; ++ii)
      __builtin_amdgcn_global_load_lds(AS1C(pG[ii] + (size_t)it * 128),
          AS3(((char*)smem) + (size_t)buf * 32768 + ldsoff[ii]), 16, 0, 0);
  };

  stage(0, 0);
  #pragma unroll
  for (int it = 0; it < 8; ++it) {
    const int cur = it & 1;
    if (it < 7) {
      stage(it + 1, cur ^ 1);
      asm volatile("s_waitcnt vmcnt(4)" ::: "memory");
    } else {
      asm volatile("s_waitcnt vmcnt(0)" ::: "memory");
    }
    __builtin_amdgcn_sched_barrier(0);
    __builtin_amdgcn_s_barrier();
    __builtin_amdgcn_sched_barrier(0);
    const _Float16* sA = smem + (size_t)cur * 16384;
    const _Float16* sB = sA + 8192;
    __builtin_amdgcn_s_setprio(1);
    #pragma unroll
    for (int kk = 0; kk < 64; kk += 32) {
      const int kcb = (kk >> 3) + (l >> 4);
      half8 a[2], b[4];
      #pragma unroll
      for (int mf = 0; mf < 2; ++mf)
        a[mf] = *(const half8*)(sA + ((size_t)kcb * 128 + wm * 32 + mf * 16 + (l & 15)) * 8);
      #pragma unroll
      for (int nf = 0; nf < 4; ++nf)
        b[nf] = *(const half8*)(sB + ((size_t)kcb * 128 + wn * 64 + nf * 16 + (l & 15)) * 8);
      #pragma unroll
      for (int mf = 0; mf < 2; ++mf)
        #pragma unroll
        for (int nf = 0; nf < 4; ++nf)
          acc[mf][nf] = __builtin_amdgcn_mfma_f32_16x16x32_f16(a[mf], b[nf], acc[mf][nf], 0, 0, 0);
    }
    __builtin_amdgcn_s_setprio(0);
    asm volatile("s_waitcnt lgkmcnt(0)" ::: "memory");
    __builtin_amdgcn_sched_barrier(0);
    __builtin_amdgcn_s_barrier();
    __builtin_amdgcn_sched_barrier(0);
  }

  // ---- epilogue: preact = acc + xp (bias already in xp); cell update -------
  const int q = (nb & 15) * 2 + wn;
  const int jj = l & 15;
  const int j = q * 16 + jj;
  const int n4b = dir * 2048 + n0 + wn * 64 + jj;   // + g*16 per gate

  #pragma unroll
  for (int mf = 0; mf < 2; ++mf) {
    #pragma unroll
    for (int reg = 0; reg < 4; ++reg) {
      int r = m0 + wm * 32 + mf * 16 + (l >> 4) * 4 + reg;   // C/D row mapping
      const _Float16* xr = xp + (size_t)r * 4096 + n4b;
      float ip = acc[mf][0][reg] + (float)xr[0];
      float fp = acc[mf][1][reg] + (float)xr[16];
      float gp = acc[mf][2][reg] + (float)xr[32];
      float op = acc[mf][3][reg] + (float)xr[48];
      size_t cidx = ((size_t)dir * 1024 + r) * 512 + j;
      float cold = cbuf[cidx];
      float cn = sigm(fp) * cold + sigm(ip) * tanh_f(gp);
      float hn = sigm(op) * tanh_f(cn);
      cbuf[cidx] = cn;
      hout[cidx] = (_Float16)hn;
      int chunk = r >> 6, bb = r & 63;
      int t = chunk * 32 + s;
      if (layer == 0) {
        out0ring[((size_t)(s & 7) * 1024 + r) * 1024 + dir * 512 + j] = (_Float16)hn;
      } else {
        outs[((size_t)bb * 512 + t) * 1024 + dir * 512 + j] = hn;
      }
      if (s == 31 && chunk == 15) {
        size_t hidx = ((size_t)(layer * 2 + dir) * 64 + bb) * 512 + j;
        hT[hidx] = hn; cT[hidx] = cn;
      }
    }
  }
}

// ---------------------------------------------------------------------------
extern "C" void kernel_launch(void* const* d_in, const int* in_sizes, int n_in,
                              void* d_out, int out_size, void* d_ws, size_t ws_size,
                              hipStream_t stream)
{
  const int*   rt  = (const int*)d_in[0];
  const int*   re  = (const int*)d_in[1];
  const int*   rm  = (const int*)d_in[2];
  const float* h0  = (const float*)d_in[3];
  const float* c0  = (const float*)d_in[4];
  const float* Ert = (const float*)d_in[5];
  const float* Ere = (const float*)d_in[6];
  const float* Erm = (const float*)d_in[7];
  const float* Wih = (const float*)d_in[8];
  const float* Whh = (const float*)d_in[9];
  const float* bih = (const float*)d_in[10];
  const float* bhh = (const float*)d_in[11];

  float* outs = (float*)d_out;                       // [B][T][D]
  float* hT = outs + (size_t)64 * 512 * 1024;        // [4][B][H]
  float* cT = hT + (size_t)4 * 64 * 512;             // [4][B][H]

  char* p = (char*)d_ws;
  _Float16* emb   = (_Float16*)p; p += (size_t)32768 * 1024 * 2;      // 64 MiB
  _Float16* Wx    = (_Float16*)p; p += (size_t)4 * 2048 * 1024 * 2;   // 16 MiB
  _Float16* Wh    = (_Float16*)p; p += (size_t)4 * 2048 * 512 * 2;    //  8 MiB
  float*    biasc = (float*)p;    p += (size_t)4 * 2048 * 4;          // 32 KiB
  _Float16* out0r = (_Float16*)p; p += (size_t)8 * 1024 * 1024 * 2;   // 16 MiB
  _Float16* hbAll = (_Float16*)p; p += (size_t)4 * 1048576 * 2;       //  8 MiB
  float*    cbAll = (float*)p;    p += (size_t)2 * 1048576 * 4;       //  8 MiB
  _Float16* xp0r  = (_Float16*)p; p += (size_t)12 * 1024 * 4096 * 2;  // 96 MiB
  _Float16* xp1r  = (_Float16*)p; p += (size_t)12 * 1024 * 4096 * 2;  // 96 MiB

  k_prepw<<<8192, 256, 0, stream>>>(Wih, Whh, Wx, Wh);
  k_prepb<<<32, 256, 0, stream>>>(bih, bhh, biasc);
  k_embed<<<16384, 256, 0, stream>>>(rt, re, rm, Ert, Ere, Erm, emb);
  k_init<<<4096, 256, 0, stream>>>(0, h0, c0, hbAll, cbAll);
  k_init<<<4096, 256, 0, stream>>>(1, h0, c0, hbAll + (size_t)2 * 1048576,
                                   cbAll + (size_t)1048576);

  // xp0 batches 0,1 upfront (cover L0 steps 0..7)
  k_xp<<<dim3(32, 32), 512, 0, stream>>>(0, 0, emb, out0r, Wx, biasc, xp0r);
  k_xp<<<dim3(32, 32), 512, 0, stream>>>(0, 1, emb, out0r, Wx, biasc, xp0r);

  // launch k: L0 step k (k<32) || L1 step k-4; xp0 batch k/4+1 before every
  // 4th launch; xp1 batch (k-3)/4 right after L0 step 4g+3 completes.
  for (int k = 0; k < 36; ++k) {
    if (k > 0 && (k & 3) == 0) {
      int b = k / 4 + 1;
      if (b < 8) k_xp<<<dim3(32, 32), 512, 0, stream>>>(0, b, emb, out0r, Wx, biasc, xp0r);
    }
    k_step<<<dim3(32, 8, 2), 512, 0, stream>>>(k, k - 4, out0r, outs,
                                               hbAll, cbAll, Wh, xp0r, xp1r, hT, cT);
    if ((k & 3) == 3 && k < 32)
      k_xp<<<dim3(32, 32), 512, 0, stream>>>(1, (k - 3) / 4, emb, out0r, Wx, biasc, xp1r);
  }
}